// Round 1
// baseline (799.364 us; speedup 1.0000x reference)
//
#include <hip/hip_runtime.h>
#include <hip/hip_bf16.h>

#define NNODES 50000
#define NEDGES 300000
#define NGRAPH 2048
#define NFEAT  128
#define NHID   256
#define DOUT   32

// ---------- setup kernels ----------
__global__ __launch_bounds__(256) void init_node_k(float* deg, int* cnt, int* fill, int n) {
    int i = blockIdx.x * 256 + threadIdx.x;
    if (i < n) { deg[i] = 1.0f; cnt[i] = 0; fill[i] = 0; }   // deg starts at 1 (self-loop)
}

__global__ __launch_bounds__(256) void edge_hist_k(const int* __restrict__ dst,
                                                   float* deg, int* cnt, int E) {
    int e = blockIdx.x * 256 + threadIdx.x;
    if (e < E) { int d = dst[e]; atomicAdd(&deg[d], 1.0f); atomicAdd(&cnt[d], 1); }
}

__global__ __launch_bounds__(256) void dinv_k(const float* __restrict__ deg, float* dinv, int n) {
    int i = blockIdx.x * 256 + threadIdx.x;
    if (i < n) dinv[i] = rsqrtf(deg[i]);   // deg >= 1 always (self-loop)
}

// single-block exclusive scan of cnt[0..n) -> rowp[0..n]
__global__ __launch_bounds__(1024) void scan_k(const int* __restrict__ cnt, int* __restrict__ rowp, int n) {
    __shared__ int sdata[1024];
    __shared__ int carry;
    int tid = threadIdx.x;
    if (tid == 0) carry = 0;
    __syncthreads();
    for (int base = 0; base < n; base += 1024) {
        int i = base + tid;
        int v = (i < n) ? cnt[i] : 0;
        sdata[tid] = v;
        __syncthreads();
        for (int off = 1; off < 1024; off <<= 1) {
            int t = (tid >= off) ? sdata[tid - off] : 0;
            __syncthreads();
            sdata[tid] += t;
            __syncthreads();
        }
        if (i < n) rowp[i] = carry + sdata[tid] - v;   // exclusive
        __syncthreads();
        if (tid == 0) carry += sdata[1023];
        __syncthreads();
    }
    if (tid == 0) rowp[n] = carry;
}

__global__ __launch_bounds__(256) void scatter_k(const int* __restrict__ src, const int* __restrict__ dst,
                                                 const int* __restrict__ rowp, int* fill,
                                                 const float* __restrict__ dinv,
                                                 int* __restrict__ col, float* __restrict__ nrm, int E) {
    int e = blockIdx.x * 256 + threadIdx.x;
    if (e < E) {
        int s = src[e], d = dst[e];
        int p = rowp[d] + atomicAdd(&fill[d], 1);
        col[p] = s;
        nrm[p] = dinv[s] * dinv[d];
    }
}

// ---------- f32 tiled GEMM: C[M,N] = A[M,K] @ B[K,N] (+bias)(+relu) ----------
// flags: bit0 = relu, bit1 = bias
__global__ __launch_bounds__(256) void gemm_k(const float* __restrict__ A, const float* __restrict__ B,
                                              const float* __restrict__ bias, float* __restrict__ C,
                                              int M, int K, int N, int flags) {
    const int BM = 64, BN = 64, BK = 16;
    __shared__ float As[BM][BK + 1];
    __shared__ float Bs[BK][BN + 1];
    int tid = threadIdx.x;
    int tx = tid & 15;          // output col group
    int ty = tid >> 4;          // output row group
    int rowBase = blockIdx.x * BM;
    int colBase = blockIdx.y * BN;
    // loader mapping
    int a_r = tid >> 2;            // 0..63
    int a_k = (tid & 3) * 4;       // 0,4,8,12
    int b_k = tid >> 4;            // 0..15
    int b_c = (tid & 15) * 4;      // 0..60

    float acc[4][4] = {};
    for (int k0 = 0; k0 < K; k0 += BK) {
        float4 av = make_float4(0.f, 0.f, 0.f, 0.f);
        int ar = rowBase + a_r;
        if (ar < M) av = *(const float4*)&A[(size_t)ar * K + k0 + a_k];
        As[a_r][a_k + 0] = av.x; As[a_r][a_k + 1] = av.y;
        As[a_r][a_k + 2] = av.z; As[a_r][a_k + 3] = av.w;

        float4 bv = make_float4(0.f, 0.f, 0.f, 0.f);
        int bc = colBase + b_c;
        if (bc < N) bv = *(const float4*)&B[(size_t)(k0 + b_k) * N + bc];
        Bs[b_k][b_c + 0] = bv.x; Bs[b_k][b_c + 1] = bv.y;
        Bs[b_k][b_c + 2] = bv.z; Bs[b_k][b_c + 3] = bv.w;
        __syncthreads();

#pragma unroll
        for (int k = 0; k < BK; ++k) {
            float a0 = As[ty * 4 + 0][k], a1 = As[ty * 4 + 1][k];
            float a2 = As[ty * 4 + 2][k], a3 = As[ty * 4 + 3][k];
            float bb0 = Bs[k][tx * 4 + 0], bb1 = Bs[k][tx * 4 + 1];
            float bb2 = Bs[k][tx * 4 + 2], bb3 = Bs[k][tx * 4 + 3];
            acc[0][0] += a0 * bb0; acc[0][1] += a0 * bb1; acc[0][2] += a0 * bb2; acc[0][3] += a0 * bb3;
            acc[1][0] += a1 * bb0; acc[1][1] += a1 * bb1; acc[1][2] += a1 * bb2; acc[1][3] += a1 * bb3;
            acc[2][0] += a2 * bb0; acc[2][1] += a2 * bb1; acc[2][2] += a2 * bb2; acc[2][3] += a2 * bb3;
            acc[3][0] += a3 * bb0; acc[3][1] += a3 * bb1; acc[3][2] += a3 * bb2; acc[3][3] += a3 * bb3;
        }
        __syncthreads();
    }
#pragma unroll
    for (int i = 0; i < 4; ++i) {
        int r = rowBase + ty * 4 + i;
        if (r >= M) continue;
#pragma unroll
        for (int j = 0; j < 4; ++j) {
            int c = colBase + tx * 4 + j;
            if (c >= N) continue;
            float v = acc[i][j];
            if (flags & 2) v += bias[c];
            if (flags & 1) v = fmaxf(v, 0.f);
            C[(size_t)r * N + c] = v;
        }
    }
}

// ---------- aggregation: h[i] = relu( sum_{e in CSR(i)} t[col[e]]*nrm[e] + t[i]*dinv[i]^2 + b ) ----------
__global__ __launch_bounds__(256) void agg_k(const float* __restrict__ t,
                                             const int* __restrict__ rowp, const int* __restrict__ col,
                                             const float* __restrict__ nrm, const float* __restrict__ dinv,
                                             const float* __restrict__ bias,
                                             float* __restrict__ h, int n) {
    int wave = threadIdx.x >> 6;
    int lane = threadIdx.x & 63;
    int node = blockIdx.x * 4 + wave;
    if (node >= n) return;
    float di = dinv[node];
    float self_w = di * di;
    float4 acc = *(const float4*)&t[(size_t)node * NHID + lane * 4];
    acc.x *= self_w; acc.y *= self_w; acc.z *= self_w; acc.w *= self_w;
    int e0 = rowp[node], e1 = rowp[node + 1];
    for (int e = e0; e < e1; ++e) {
        int s = col[e];
        float w = nrm[e];
        float4 m = *(const float4*)&t[(size_t)s * NHID + lane * 4];
        acc.x += m.x * w; acc.y += m.y * w; acc.z += m.z * w; acc.w += m.w * w;
    }
    float4 b4 = *(const float4*)&bias[lane * 4];
    acc.x = fmaxf(acc.x + b4.x, 0.f);
    acc.y = fmaxf(acc.y + b4.y, 0.f);
    acc.z = fmaxf(acc.z + b4.z, 0.f);
    acc.w = fmaxf(acc.w + b4.w, 0.f);
    *(float4*)&h[(size_t)node * NHID + lane * 4] = acc;
}

// ---------- pooling ----------
__global__ __launch_bounds__(256) void bounds_k(const int* __restrict__ batch, int* gstart, int n, int G) {
    int g = blockIdx.x * 256 + threadIdx.x;
    if (g > G) return;
    int lo = 0, hi = n;
    while (lo < hi) { int mid = (lo + hi) >> 1; if (batch[mid] < g) lo = mid + 1; else hi = mid; }
    gstart[g] = lo;
}

__global__ __launch_bounds__(256) void pool_k(const float* __restrict__ h, const int* __restrict__ gstart,
                                              float* __restrict__ hg) {
    int g = blockIdx.x;
    int ch = threadIdx.x;
    int s = gstart[g], e = gstart[g + 1];
    float acc = 0.f;
    for (int nidx = s; nidx < e; ++nidx) acc += h[(size_t)nidx * NHID + ch];
    float cnt = (float)(e - s);
    hg[(size_t)g * NHID + ch] = acc / fmaxf(cnt, 1.0f);
}

extern "C" void kernel_launch(void* const* d_in, const int* in_sizes, int n_in,
                              void* d_out, int out_size, void* d_ws, size_t ws_size,
                              hipStream_t stream) {
    const float* x    = (const float*)d_in[0];
    const int*   ei   = (const int*)d_in[1];   // [2, E] row-major: src then dst
    const int*   batch= (const int*)d_in[2];
    const float* W1   = (const float*)d_in[3];
    const float* b1   = (const float*)d_in[4];
    const float* W2   = (const float*)d_in[5];
    const float* b2   = (const float*)d_in[6];
    const float* W3   = (const float*)d_in[7];
    const float* b3   = (const float*)d_in[8];
    const float* Wf1  = (const float*)d_in[9];
    const float* bf1  = (const float*)d_in[10];
    const float* Wf2  = (const float*)d_in[11];
    const float* bf2  = (const float*)d_in[12];
    float* out = (float*)d_out;

    const int* e_src = ei;
    const int* e_dst = ei + NEDGES;

    char* ws = (char*)d_ws;
    size_t off = 0;
    auto alloc = [&](size_t bytes) -> void* {
        void* p = (void*)(ws + off);
        off += (bytes + 255) & ~(size_t)255;
        return p;
    };
    float* P    = (float*)alloc((size_t)NNODES * NHID * 4);   // 51.2 MB
    float* Q    = (float*)alloc((size_t)NNODES * NHID * 4);   // 51.2 MB
    float* deg  = (float*)alloc((size_t)NNODES * 4);
    float* dinv = (float*)alloc((size_t)NNODES * 4);
    int*   cnt  = (int*)alloc((size_t)NNODES * 4);
    int*   fill = (int*)alloc((size_t)NNODES * 4);
    int*   rowp = (int*)alloc((size_t)(NNODES + 1) * 4);
    int*   col  = (int*)alloc((size_t)NEDGES * 4);
    float* nrm  = (float*)alloc((size_t)NEDGES * 4);
    int*   gst  = (int*)alloc((size_t)(NGRAPH + 1) * 4);
    float* hg   = (float*)alloc((size_t)NGRAPH * NHID * 4);
    float* hr   = (float*)alloc((size_t)NGRAPH * NFEAT * 4);

    // ---- GCN norm + CSR build ----
    hipLaunchKernelGGL(init_node_k, dim3((NNODES + 255) / 256), dim3(256), 0, stream, deg, cnt, fill, NNODES);
    hipLaunchKernelGGL(edge_hist_k, dim3((NEDGES + 255) / 256), dim3(256), 0, stream, e_dst, deg, cnt, NEDGES);
    hipLaunchKernelGGL(dinv_k, dim3((NNODES + 255) / 256), dim3(256), 0, stream, deg, dinv, NNODES);
    hipLaunchKernelGGL(scan_k, dim3(1), dim3(1024), 0, stream, cnt, rowp, NNODES);
    hipLaunchKernelGGL(scatter_k, dim3((NEDGES + 255) / 256), dim3(256), 0, stream,
                       e_src, e_dst, rowp, fill, dinv, col, nrm, NEDGES);

    // ---- layer 1: t = x@W1 ; h1 = relu(agg + b1) ----
    hipLaunchKernelGGL(gemm_k, dim3((NNODES + 63) / 64, NHID / 64), dim3(256), 0, stream,
                       x, W1, (const float*)nullptr, P, NNODES, NFEAT, NHID, 0);
    hipLaunchKernelGGL(agg_k, dim3((NNODES + 3) / 4), dim3(256), 0, stream,
                       P, rowp, col, nrm, dinv, b1, Q, NNODES);
    // ---- layer 2 ----
    hipLaunchKernelGGL(gemm_k, dim3((NNODES + 63) / 64, NHID / 64), dim3(256), 0, stream,
                       Q, W2, (const float*)nullptr, P, NNODES, NHID, NHID, 0);
    hipLaunchKernelGGL(agg_k, dim3((NNODES + 3) / 4), dim3(256), 0, stream,
                       P, rowp, col, nrm, dinv, b2, Q, NNODES);
    // ---- layer 3 ----
    hipLaunchKernelGGL(gemm_k, dim3((NNODES + 63) / 64, NHID / 64), dim3(256), 0, stream,
                       Q, W3, (const float*)nullptr, P, NNODES, NHID, NHID, 0);
    hipLaunchKernelGGL(agg_k, dim3((NNODES + 3) / 4), dim3(256), 0, stream,
                       P, rowp, col, nrm, dinv, b3, Q, NNODES);

    // ---- global mean pool ----
    hipLaunchKernelGGL(bounds_k, dim3((NGRAPH + 1 + 255) / 256), dim3(256), 0, stream, batch, gst, NNODES, NGRAPH);
    hipLaunchKernelGGL(pool_k, dim3(NGRAPH), dim3(256), 0, stream, Q, gst, hg);

    // ---- MLP head ----
    hipLaunchKernelGGL(gemm_k, dim3((NGRAPH + 63) / 64, (NFEAT + 63) / 64), dim3(256), 0, stream,
                       hg, Wf1, bf1, hr, NGRAPH, NHID, NFEAT, 3);
    hipLaunchKernelGGL(gemm_k, dim3((NGRAPH + 63) / 64, (DOUT + 63) / 64), dim3(256), 0, stream,
                       hr, Wf2, bf2, out, NGRAPH, NFEAT, DOUT, 2);
}

// Round 2
// 441.879 us; speedup vs baseline: 1.8090x; 1.8090x over previous
//
#include <hip/hip_runtime.h>
#include <hip/hip_bf16.h>

#define NNODES 50000
#define NEDGES 300000
#define NGRAPH 2048
#define NFEAT  128
#define NHID   256
#define DOUT   32

typedef __bf16 bf16x8 __attribute__((ext_vector_type(8)));
typedef float  f32x4  __attribute__((ext_vector_type(4)));

__device__ __forceinline__ float bf2f(unsigned short u) {
    return __uint_as_float(((unsigned)u) << 16);
}
__device__ __forceinline__ unsigned short f2bf(float f) {
    unsigned u = __float_as_uint(f);
    unsigned r = u + 0x7FFFu + ((u >> 16) & 1u);   // RNE
    return (unsigned short)(r >> 16);
}

// ---------- setup kernels ----------
__global__ __launch_bounds__(256) void init_node_k(int* cnt, int* fill, int n) {
    int i = blockIdx.x * 256 + threadIdx.x;
    if (i < n) { cnt[i] = 0; fill[i] = 0; }
}

__global__ __launch_bounds__(256) void edge_hist_k(const int* __restrict__ dst, int* cnt, int E) {
    int e = blockIdx.x * 256 + threadIdx.x;
    if (e < E) atomicAdd(&cnt[dst[e]], 1);
}

__global__ __launch_bounds__(256) void dinv_k(const int* __restrict__ cnt, float* dinv, int n) {
    int i = blockIdx.x * 256 + threadIdx.x;
    if (i < n) dinv[i] = rsqrtf((float)(cnt[i] + 1));   // +1 self loop, deg>=1 always
}

// hierarchical exclusive scan: block scans -> partial scan -> add offsets
__global__ __launch_bounds__(1024) void scan_block_k(const int* __restrict__ cnt, int* __restrict__ rowp,
                                                     int* __restrict__ part, int n) {
    __shared__ int s[1024];
    int tid = threadIdx.x;
    int i = blockIdx.x * 1024 + tid;
    int v = (i < n) ? cnt[i] : 0;
    s[tid] = v;
    __syncthreads();
    for (int off = 1; off < 1024; off <<= 1) {
        int t = (tid >= off) ? s[tid - off] : 0;
        __syncthreads();
        s[tid] += t;
        __syncthreads();
    }
    if (i < n) rowp[i] = s[tid] - v;           // exclusive, pre-carry
    if (tid == 1023) part[blockIdx.x] = s[1023];
}

__global__ __launch_bounds__(64) void scan_part_k(int* part, int nb) {
    if (threadIdx.x == 0) {
        int acc = 0;
        for (int b = 0; b < nb; ++b) { int t = part[b]; part[b] = acc; acc += t; }
        part[nb] = acc;
    }
}

__global__ __launch_bounds__(256) void scan_add_k(int* __restrict__ rowp, const int* __restrict__ part,
                                                  int n, int nb) {
    int i = blockIdx.x * 256 + threadIdx.x;
    if (i < n) rowp[i] += part[i >> 10];
    else if (i == n) rowp[n] = part[nb];
}

__global__ __launch_bounds__(256) void scatter_k(const int* __restrict__ src, const int* __restrict__ dst,
                                                 const int* __restrict__ rowp, int* fill,
                                                 const float* __restrict__ dinv,
                                                 int* __restrict__ col, float* __restrict__ nrm, int E) {
    int e = blockIdx.x * 256 + threadIdx.x;
    if (e < E) {
        int s = src[e], d = dst[e];
        int p = rowp[d] + atomicAdd(&fill[d], 1);
        col[p] = s;
        nrm[p] = dinv[s] * dinv[d];
    }
}

// ---------- casts ----------
__global__ __launch_bounds__(256) void cast_x_k(const float* __restrict__ x, unsigned short* __restrict__ x16, int n) {
    int i = (blockIdx.x * 256 + threadIdx.x) * 8;
    if (i >= n) return;
    float4 a = *(const float4*)&x[i];
    float4 b = *(const float4*)&x[i + 4];
    ushort4 lo = { f2bf(a.x), f2bf(a.y), f2bf(a.z), f2bf(a.w) };
    ushort4 hi = { f2bf(b.x), f2bf(b.y), f2bf(b.z), f2bf(b.w) };
    *(ushort4*)&x16[i] = lo;
    *(ushort4*)&x16[i + 4] = hi;
}

// W [K,N] f32 row-major -> Wt [N,K] bf16
__global__ __launch_bounds__(256) void cast_wt_k(const float* __restrict__ W, unsigned short* __restrict__ Wt,
                                                 int K, int N) {
    int idx = blockIdx.x * 256 + threadIdx.x;
    if (idx >= N * K) return;
    int n = idx / K, k = idx - n * K;
    Wt[idx] = f2bf(W[(size_t)k * N + n]);
}

// ---------- bf16 MFMA GEMM: C[M,N] = A[M,K] @ Bt[N,K]^T ----------
// flags: bit0 = relu, bit1 = bias, bit2 = f32 output (else bf16)
#define LDSW 40   // padded row stride (bf16 units) to spread LDS banks
__global__ __launch_bounds__(256) void gemm_k(const unsigned short* __restrict__ A,
                                              const unsigned short* __restrict__ Bt,
                                              const float* __restrict__ bias, void* __restrict__ C,
                                              int M, int N, int K, int flags) {
    __shared__ unsigned short As[128 * LDSW];
    __shared__ unsigned short Bs[128 * LDSW];
    const int tid = threadIdx.x;
    const int lane = tid & 63;
    const int wave = tid >> 6;
    const int wr = (wave >> 1) * 64;     // wave row offset in 128x128 tile
    const int wc = (wave & 1) * 64;      // wave col offset
    const int m = lane & 15;
    const int q = lane >> 4;
    const int rowBase = blockIdx.x * 128;
    const int colBase = blockIdx.y * 128;

    // staging map: thread t loads 32B (16 bf16) of one row: row = t>>1, kbase = (t&1)*16
    const int srow = tid >> 1;
    const int skb  = (tid & 1) * 16;

    f32x4 acc[4][4] = {};

    for (int kt = 0; kt < K; kt += 32) {
        // --- stage A ---
        {
            int gr = rowBase + srow;
            float4 v = make_float4(0.f, 0.f, 0.f, 0.f), w = v;
            if (gr < M) {
                const float4* p = (const float4*)&A[(size_t)gr * K + kt + skb];
                v = p[0]; w = p[1];
            }
            *(float4*)&As[srow * LDSW + skb]     = v;
            *(float4*)&As[srow * LDSW + skb + 8] = w;
        }
        // --- stage B (Bt rows are C columns) ---
        {
            int gc = colBase + srow;
            float4 v = make_float4(0.f, 0.f, 0.f, 0.f), w = v;
            if (gc < N) {
                const float4* p = (const float4*)&Bt[(size_t)gc * K + kt + skb];
                v = p[0]; w = p[1];
            }
            *(float4*)&Bs[srow * LDSW + skb]     = v;
            *(float4*)&Bs[srow * LDSW + skb + 8] = w;
        }
        __syncthreads();

        bf16x8 af[4], bf[4];
#pragma unroll
        for (int i = 0; i < 4; ++i)
            af[i] = *(const bf16x8*)&As[(wr + i * 16 + m) * LDSW + q * 8];
#pragma unroll
        for (int j = 0; j < 4; ++j)
            bf[j] = *(const bf16x8*)&Bs[(wc + j * 16 + m) * LDSW + q * 8];
#pragma unroll
        for (int i = 0; i < 4; ++i)
#pragma unroll
            for (int j = 0; j < 4; ++j)
                acc[i][j] = __builtin_amdgcn_mfma_f32_16x16x32_bf16(af[i], bf[j], acc[i][j], 0, 0, 0);
        __syncthreads();
    }

    // epilogue: D row = quad*4+reg, col = lane&15  (m89-verified layout)
#pragma unroll
    for (int i = 0; i < 4; ++i) {
#pragma unroll
        for (int j = 0; j < 4; ++j) {
            int c = colBase + wc + j * 16 + m;
            if (c >= N) continue;
            float bv = (flags & 2) ? bias[c] : 0.f;
#pragma unroll
            for (int r = 0; r < 4; ++r) {
                int rr = rowBase + wr + i * 16 + q * 4 + r;
                if (rr >= M) continue;
                float v = acc[i][j][r] + bv;
                if (flags & 1) v = fmaxf(v, 0.f);
                if (flags & 4) ((float*)C)[(size_t)rr * N + c] = v;
                else ((unsigned short*)C)[(size_t)rr * N + c] = f2bf(v);
            }
        }
    }
}

// ---------- aggregation (bf16 in/out, f32 accum): h[i]=relu(sum msg + self + b) ----------
__global__ __launch_bounds__(256) void agg_k(const unsigned short* __restrict__ t,
                                             const int* __restrict__ rowp, const int* __restrict__ col,
                                             const float* __restrict__ nrm, const float* __restrict__ dinv,
                                             const float* __restrict__ bias,
                                             unsigned short* __restrict__ h, int n) {
    int wave = threadIdx.x >> 6;
    int lane = threadIdx.x & 63;
    int node = blockIdx.x * 4 + wave;
    if (node >= n) return;
    float di = dinv[node];
    float sw = di * di;
    ushort4 u = ((const ushort4*)(t + (size_t)node * NHID))[lane];
    float ax = bf2f(u.x) * sw, ay = bf2f(u.y) * sw, az = bf2f(u.z) * sw, aw = bf2f(u.w) * sw;
    int e0 = rowp[node], e1 = rowp[node + 1];
    for (int e = e0; e < e1; ++e) {
        int s = col[e];
        float w = nrm[e];
        ushort4 mm = ((const ushort4*)(t + (size_t)s * NHID))[lane];
        ax += bf2f(mm.x) * w; ay += bf2f(mm.y) * w;
        az += bf2f(mm.z) * w; aw += bf2f(mm.w) * w;
    }
    float4 b4 = *(const float4*)&bias[lane * 4];
    ushort4 o;
    o.x = f2bf(fmaxf(ax + b4.x, 0.f));
    o.y = f2bf(fmaxf(ay + b4.y, 0.f));
    o.z = f2bf(fmaxf(az + b4.z, 0.f));
    o.w = f2bf(fmaxf(aw + b4.w, 0.f));
    ((ushort4*)(h + (size_t)node * NHID))[lane] = o;
}

// ---------- pooling ----------
__global__ __launch_bounds__(256) void bounds_k(const int* __restrict__ batch, int* gstart, int n, int G) {
    int g = blockIdx.x * 256 + threadIdx.x;
    if (g > G) return;
    int lo = 0, hi = n;
    while (lo < hi) { int mid = (lo + hi) >> 1; if (batch[mid] < g) lo = mid + 1; else hi = mid; }
    gstart[g] = lo;
}

__global__ __launch_bounds__(256) void pool_k(const unsigned short* __restrict__ h,
                                              const int* __restrict__ gstart,
                                              unsigned short* __restrict__ hg) {
    int g = blockIdx.x;
    int ch = threadIdx.x;
    int s = gstart[g], e = gstart[g + 1];
    float acc = 0.f;
    for (int i = s; i < e; ++i) acc += bf2f(h[(size_t)i * NHID + ch]);
    hg[(size_t)g * NHID + ch] = f2bf(acc / fmaxf((float)(e - s), 1.0f));
}

extern "C" void kernel_launch(void* const* d_in, const int* in_sizes, int n_in,
                              void* d_out, int out_size, void* d_ws, size_t ws_size,
                              hipStream_t stream) {
    const float* x    = (const float*)d_in[0];
    const int*   ei   = (const int*)d_in[1];
    const int*   batch= (const int*)d_in[2];
    const float* W1   = (const float*)d_in[3];
    const float* b1   = (const float*)d_in[4];
    const float* W2   = (const float*)d_in[5];
    const float* b2   = (const float*)d_in[6];
    const float* W3   = (const float*)d_in[7];
    const float* b3   = (const float*)d_in[8];
    const float* Wf1  = (const float*)d_in[9];
    const float* bf1  = (const float*)d_in[10];
    const float* Wf2  = (const float*)d_in[11];
    const float* bf2  = (const float*)d_in[12];
    float* out = (float*)d_out;

    const int* e_src = ei;
    const int* e_dst = ei + NEDGES;

    char* ws = (char*)d_ws;
    size_t off = 0;
    auto alloc = [&](size_t bytes) -> void* {
        void* p = (void*)(ws + off);
        off += (bytes + 255) & ~(size_t)255;
        return p;
    };
    unsigned short* X16 = (unsigned short*)alloc((size_t)NNODES * NFEAT * 2);
    unsigned short* T16 = (unsigned short*)alloc((size_t)NNODES * NHID * 2);
    unsigned short* H16 = (unsigned short*)alloc((size_t)NNODES * NHID * 2);
    unsigned short* Wt1 = (unsigned short*)alloc((size_t)NHID * NFEAT * 2);
    unsigned short* Wt2 = (unsigned short*)alloc((size_t)NHID * NHID * 2);
    unsigned short* Wt3 = (unsigned short*)alloc((size_t)NHID * NHID * 2);
    unsigned short* Wf1t= (unsigned short*)alloc((size_t)NFEAT * NHID * 2);
    unsigned short* Wf2t= (unsigned short*)alloc((size_t)DOUT * NFEAT * 2);
    unsigned short* HG  = (unsigned short*)alloc((size_t)NGRAPH * NHID * 2);
    unsigned short* HR  = (unsigned short*)alloc((size_t)NGRAPH * NFEAT * 2);
    float* dinv = (float*)alloc((size_t)NNODES * 4);
    int*   cnt  = (int*)alloc((size_t)NNODES * 4);
    int*   fill = (int*)alloc((size_t)NNODES * 4);
    int*   rowp = (int*)alloc((size_t)(NNODES + 1) * 4);
    int*   col  = (int*)alloc((size_t)NEDGES * 4);
    float* nrm  = (float*)alloc((size_t)NEDGES * 4);
    int*   part = (int*)alloc((size_t)64 * 4);
    int*   gst  = (int*)alloc((size_t)(NGRAPH + 1) * 4);

    const int nb = (NNODES + 1023) / 1024;   // 49

    // ---- GCN norm + CSR ----
    hipLaunchKernelGGL(init_node_k, dim3((NNODES + 255) / 256), dim3(256), 0, stream, cnt, fill, NNODES);
    hipLaunchKernelGGL(edge_hist_k, dim3((NEDGES + 255) / 256), dim3(256), 0, stream, e_dst, cnt, NEDGES);
    hipLaunchKernelGGL(dinv_k, dim3((NNODES + 255) / 256), dim3(256), 0, stream, cnt, dinv, NNODES);
    hipLaunchKernelGGL(scan_block_k, dim3(nb), dim3(1024), 0, stream, cnt, rowp, part, NNODES);
    hipLaunchKernelGGL(scan_part_k, dim3(1), dim3(64), 0, stream, part, nb);
    hipLaunchKernelGGL(scan_add_k, dim3((NNODES + 1 + 255) / 256), dim3(256), 0, stream, rowp, part, NNODES, nb);
    hipLaunchKernelGGL(scatter_k, dim3((NEDGES + 255) / 256), dim3(256), 0, stream,
                       e_src, e_dst, rowp, fill, dinv, col, nrm, NEDGES);

    // ---- casts ----
    hipLaunchKernelGGL(cast_x_k, dim3((NNODES * NFEAT / 8 + 255) / 256), dim3(256), 0, stream,
                       x, X16, NNODES * NFEAT);
    hipLaunchKernelGGL(cast_wt_k, dim3((NHID * NFEAT + 255) / 256), dim3(256), 0, stream, W1, Wt1, NFEAT, NHID);
    hipLaunchKernelGGL(cast_wt_k, dim3((NHID * NHID + 255) / 256), dim3(256), 0, stream, W2, Wt2, NHID, NHID);
    hipLaunchKernelGGL(cast_wt_k, dim3((NHID * NHID + 255) / 256), dim3(256), 0, stream, W3, Wt3, NHID, NHID);
    hipLaunchKernelGGL(cast_wt_k, dim3((NFEAT * NHID + 255) / 256), dim3(256), 0, stream, Wf1, Wf1t, NHID, NFEAT);
    hipLaunchKernelGGL(cast_wt_k, dim3((DOUT * NFEAT + 255) / 256), dim3(256), 0, stream, Wf2, Wf2t, NFEAT, DOUT);

    const dim3 gemmBlk(256);
    // ---- layer 1 ----
    hipLaunchKernelGGL(gemm_k, dim3((NNODES + 127) / 128, NHID / 128), gemmBlk, 0, stream,
                       X16, Wt1, (const float*)nullptr, T16, NNODES, NHID, NFEAT, 0);
    hipLaunchKernelGGL(agg_k, dim3((NNODES + 3) / 4), dim3(256), 0, stream,
                       T16, rowp, col, nrm, dinv, b1, H16, NNODES);
    // ---- layer 2 ----
    hipLaunchKernelGGL(gemm_k, dim3((NNODES + 127) / 128, NHID / 128), gemmBlk, 0, stream,
                       H16, Wt2, (const float*)nullptr, T16, NNODES, NHID, NHID, 0);
    hipLaunchKernelGGL(agg_k, dim3((NNODES + 3) / 4), dim3(256), 0, stream,
                       T16, rowp, col, nrm, dinv, b2, H16, NNODES);
    // ---- layer 3 ----
    hipLaunchKernelGGL(gemm_k, dim3((NNODES + 127) / 128, NHID / 128), gemmBlk, 0, stream,
                       H16, Wt3, (const float*)nullptr, T16, NNODES, NHID, NHID, 0);
    hipLaunchKernelGGL(agg_k, dim3((NNODES + 3) / 4), dim3(256), 0, stream,
                       T16, rowp, col, nrm, dinv, b3, H16, NNODES);

    // ---- pool ----
    hipLaunchKernelGGL(bounds_k, dim3((NGRAPH + 1 + 255) / 256), dim3(256), 0, stream, batch, gst, NNODES, NGRAPH);
    hipLaunchKernelGGL(pool_k, dim3(NGRAPH), dim3(256), 0, stream, H16, gst, HG);

    // ---- MLP head ----
    hipLaunchKernelGGL(gemm_k, dim3(NGRAPH / 128, 1), gemmBlk, 0, stream,
                       HG, Wf1t, bf1, HR, NGRAPH, NFEAT, NHID, 3);
    hipLaunchKernelGGL(gemm_k, dim3(NGRAPH / 128, 1), gemmBlk, 0, stream,
                       HR, Wf2t, bf2, out, NGRAPH, DOUT, NFEAT, 6);
}

// Round 3
// 391.986 us; speedup vs baseline: 2.0393x; 1.1273x over previous
//
#include <hip/hip_runtime.h>
#include <hip/hip_bf16.h>

#define NNODES 50000
#define NEDGES 300000
#define NGRAPH 2048
#define NFEAT  128
#define NHID   256
#define DOUT   32

typedef __bf16 bf16x8 __attribute__((ext_vector_type(8)));
typedef float  f32x4  __attribute__((ext_vector_type(4)));
typedef __attribute__((address_space(1))) const void* gas_ptr;
typedef __attribute__((address_space(3))) void* las_ptr;

__device__ __forceinline__ float bf2f(unsigned short u) {
    return __uint_as_float(((unsigned)u) << 16);
}
__device__ __forceinline__ unsigned short f2bf(float f) {
    unsigned u = __float_as_uint(f);
    unsigned r = u + 0x7FFFu + ((u >> 16) & 1u);   // RNE
    return (unsigned short)(r >> 16);
}

// ---------- setup kernels ----------
__global__ __launch_bounds__(256) void init_node_k(int* cnt, int* fill, int n) {
    int i = blockIdx.x * 256 + threadIdx.x;
    if (i < n) { cnt[i] = 0; fill[i] = 0; }
}

__global__ __launch_bounds__(256) void edge_hist_k(const int* __restrict__ dst, int* cnt, int E) {
    int e = blockIdx.x * 256 + threadIdx.x;
    if (e < E) atomicAdd(&cnt[dst[e]], 1);
}

__global__ __launch_bounds__(256) void dinv_k(const int* __restrict__ cnt, float* dinv, int n) {
    int i = blockIdx.x * 256 + threadIdx.x;
    if (i < n) dinv[i] = rsqrtf((float)(cnt[i] + 1));   // +1 self loop
}

// hierarchical exclusive scan
__global__ __launch_bounds__(1024) void scan_block_k(const int* __restrict__ cnt, int* __restrict__ rowp,
                                                     int* __restrict__ part, int n) {
    __shared__ int s[1024];
    int tid = threadIdx.x;
    int i = blockIdx.x * 1024 + tid;
    int v = (i < n) ? cnt[i] : 0;
    s[tid] = v;
    __syncthreads();
    for (int off = 1; off < 1024; off <<= 1) {
        int t = (tid >= off) ? s[tid - off] : 0;
        __syncthreads();
        s[tid] += t;
        __syncthreads();
    }
    if (i < n) rowp[i] = s[tid] - v;
    if (tid == 1023) part[blockIdx.x] = s[1023];
}

__global__ __launch_bounds__(64) void scan_part_k(int* part, int nb) {
    if (threadIdx.x == 0) {
        int acc = 0;
        for (int b = 0; b < nb; ++b) { int t = part[b]; part[b] = acc; acc += t; }
        part[nb] = acc;
    }
}

__global__ __launch_bounds__(256) void scan_add_k(int* __restrict__ rowp, const int* __restrict__ part,
                                                  int n, int nb) {
    int i = blockIdx.x * 256 + threadIdx.x;
    if (i < n) rowp[i] += part[i >> 10];
    else if (i == n) rowp[n] = part[nb];
}

__global__ __launch_bounds__(256) void scatter_k(const int* __restrict__ src, const int* __restrict__ dst,
                                                 const int* __restrict__ rowp, int* fill,
                                                 const float* __restrict__ dinv,
                                                 int* __restrict__ col, float* __restrict__ nrm, int E) {
    int e = blockIdx.x * 256 + threadIdx.x;
    if (e < E) {
        int s = src[e], d = dst[e];
        int p = rowp[d] + atomicAdd(&fill[d], 1);
        col[p] = s;
        nrm[p] = dinv[s] * dinv[d];
    }
}

// ---------- casts ----------
__global__ __launch_bounds__(256) void cast_x_k(const float* __restrict__ x, unsigned short* __restrict__ x16, int n) {
    int i = (blockIdx.x * 256 + threadIdx.x) * 8;
    if (i >= n) return;
    float4 a = *(const float4*)&x[i];
    float4 b = *(const float4*)&x[i + 4];
    ushort4 lo = { f2bf(a.x), f2bf(a.y), f2bf(a.z), f2bf(a.w) };
    ushort4 hi = { f2bf(b.x), f2bf(b.y), f2bf(b.z), f2bf(b.w) };
    *(ushort4*)&x16[i] = lo;
    *(ushort4*)&x16[i + 4] = hi;
}

// all 5 weight transposes in one launch. Wt[n*K+k] = W[k*N+n]
__global__ __launch_bounds__(256) void cast_all_k(const float* __restrict__ W1, const float* __restrict__ W2,
                                                  const float* __restrict__ W3, const float* __restrict__ Wf1,
                                                  const float* __restrict__ Wf2,
                                                  unsigned short* __restrict__ Wt1, unsigned short* __restrict__ Wt2,
                                                  unsigned short* __restrict__ Wt3, unsigned short* __restrict__ Wf1t,
                                                  unsigned short* __restrict__ Wf2t) {
    int idx = blockIdx.x * 256 + threadIdx.x;
    const float* W; unsigned short* Wt; int K, N, base;
    if      (idx <  32768) { W = W1;  Wt = Wt1;  K = 128; N = 256; base = 0; }
    else if (idx <  98304) { W = W2;  Wt = Wt2;  K = 256; N = 256; base = 32768; }
    else if (idx < 163840) { W = W3;  Wt = Wt3;  K = 256; N = 256; base = 98304; }
    else if (idx < 196608) { W = Wf1; Wt = Wf1t; K = 256; N = 128; base = 163840; }
    else if (idx < 200704) { W = Wf2; Wt = Wf2t; K = 128; N = 32;  base = 196608; }
    else return;
    int i = idx - base; int n = i / K, k = i - n * K;
    Wt[i] = f2bf(W[(size_t)k * N + n]);
}

// ---------- bf16 MFMA GEMM: C[M,N] = A[M,K] @ Bt[N,K]^T ----------
// m97-style: global_load_lds width-16 into unpadded [128][32] bf16 tiles.
// flags: bit0 = relu, bit1 = bias, bit2 = f32 output (else bf16)
// NOTE: tile rows/cols beyond M/N are over-read (harmless: stays inside d_ws,
// and their accumulators are never stored). K must be a multiple of 32.
__global__ __launch_bounds__(256) void gemm_k(const unsigned short* __restrict__ A,
                                              const unsigned short* __restrict__ Bt,
                                              const float* __restrict__ bias, void* __restrict__ C,
                                              int M, int N, int K, int flags) {
    __shared__ unsigned short As[128 * 32];   // 8 KB
    __shared__ unsigned short Bs[128 * 32];   // 8 KB
    const int tid = threadIdx.x;
    const int lane = tid & 63;
    const int wave = tid >> 6;
    const int wr = (wave >> 1) * 64;
    const int wc = (wave & 1) * 64;
    const int m = lane & 15;
    const int q = lane >> 4;
    const int rowBase = blockIdx.x * 128;
    const int colBase = blockIdx.y * 128;

    // chunk c in [0,512): row = c>>2, kb = (c&3)*8 bf16. Thread covers chunks tid, tid+256.
    const int r0  = tid >> 2;            // 0..63
    const int kb0 = (tid & 3) * 8;

    f32x4 acc[4][4] = {};

    for (int kt = 0; kt < K; kt += 32) {
        const unsigned short* ga0 = &A [(size_t)(rowBase + r0)       * K + kt + kb0];
        const unsigned short* ga1 = &A [(size_t)(rowBase + 64 + r0)  * K + kt + kb0];
        const unsigned short* gb0 = &Bt[(size_t)(colBase + r0)       * K + kt + kb0];
        const unsigned short* gb1 = &Bt[(size_t)(colBase + 64 + r0)  * K + kt + kb0];
        __builtin_amdgcn_global_load_lds((gas_ptr)ga0, (las_ptr)&As[wave * 512],        16, 0, 0);
        __builtin_amdgcn_global_load_lds((gas_ptr)ga1, (las_ptr)&As[2048 + wave * 512], 16, 0, 0);
        __builtin_amdgcn_global_load_lds((gas_ptr)gb0, (las_ptr)&Bs[wave * 512],        16, 0, 0);
        __builtin_amdgcn_global_load_lds((gas_ptr)gb1, (las_ptr)&Bs[2048 + wave * 512], 16, 0, 0);
        __syncthreads();

        bf16x8 af[4], bfr[4];
#pragma unroll
        for (int i = 0; i < 4; ++i)
            af[i] = *(const bf16x8*)&As[(wr + i * 16 + m) * 32 + q * 8];
#pragma unroll
        for (int j = 0; j < 4; ++j)
            bfr[j] = *(const bf16x8*)&Bs[(wc + j * 16 + m) * 32 + q * 8];
#pragma unroll
        for (int i = 0; i < 4; ++i)
#pragma unroll
            for (int j = 0; j < 4; ++j)
                acc[i][j] = __builtin_amdgcn_mfma_f32_16x16x32_bf16(af[i], bfr[j], acc[i][j], 0, 0, 0);
        __syncthreads();
    }

    // epilogue: D row = q*4+reg, col = lane&15 (m89-verified)
#pragma unroll
    for (int i = 0; i < 4; ++i) {
#pragma unroll
        for (int j = 0; j < 4; ++j) {
            int c = colBase + wc + j * 16 + m;
            if (c >= N) continue;
            float bv = (flags & 2) ? bias[c] : 0.f;
#pragma unroll
            for (int r = 0; r < 4; ++r) {
                int rr = rowBase + wr + i * 16 + q * 4 + r;
                if (rr >= M) continue;
                float v = acc[i][j][r] + bv;
                if (flags & 1) v = fmaxf(v, 0.f);
                if (flags & 4) ((float*)C)[(size_t)rr * N + c] = v;
                else ((unsigned short*)C)[(size_t)rr * N + c] = f2bf(v);
            }
        }
    }
}

// ---------- aggregation: unroll-by-8 to break gather latency chain ----------
__global__ __launch_bounds__(256) void agg_k(const unsigned short* __restrict__ t,
                                             const int* __restrict__ rowp, const int* __restrict__ col,
                                             const float* __restrict__ nrm, const float* __restrict__ dinv,
                                             const float* __restrict__ bias,
                                             unsigned short* __restrict__ h, int n) {
    int wave = threadIdx.x >> 6;
    int lane = threadIdx.x & 63;
    int node = blockIdx.x * 4 + wave;
    if (node >= n) return;
    float di = dinv[node];
    float sw = di * di;
    const ushort4* tp = (const ushort4*)t;
    ushort4 u = tp[(size_t)node * 64 + lane];
    float ax = bf2f(u.x) * sw, ay = bf2f(u.y) * sw, az = bf2f(u.z) * sw, aw = bf2f(u.w) * sw;
    int e0 = rowp[node], e1 = rowp[node + 1];
    for (int e = e0; e < e1; e += 8) {
        int   c[8]; float w[8];
#pragma unroll
        for (int j = 0; j < 8; ++j) {
            int ee = e + j;
            bool v = ee < e1;
            c[j] = v ? col[ee] : 0;     // index select BEFORE address calc: safe vs poison
            w[j] = v ? nrm[ee] : 0.f;
        }
        ushort4 mm[8];
#pragma unroll
        for (int j = 0; j < 8; ++j) mm[j] = tp[(size_t)c[j] * 64 + lane];
#pragma unroll
        for (int j = 0; j < 8; ++j) {
            ax += bf2f(mm[j].x) * w[j]; ay += bf2f(mm[j].y) * w[j];
            az += bf2f(mm[j].z) * w[j]; aw += bf2f(mm[j].w) * w[j];
        }
    }
    float4 b4 = *(const float4*)&bias[lane * 4];
    ushort4 o;
    o.x = f2bf(fmaxf(ax + b4.x, 0.f));
    o.y = f2bf(fmaxf(ay + b4.y, 0.f));
    o.z = f2bf(fmaxf(az + b4.z, 0.f));
    o.w = f2bf(fmaxf(aw + b4.w, 0.f));
    ((ushort4*)(h + (size_t)node * NHID))[lane] = o;
}

// ---------- pooling ----------
__global__ __launch_bounds__(256) void bounds_k(const int* __restrict__ batch, int* gstart, int n, int G) {
    int g = blockIdx.x * 256 + threadIdx.x;
    if (g > G) return;
    int lo = 0, hi = n;
    while (lo < hi) { int mid = (lo + hi) >> 1; if (batch[mid] < g) lo = mid + 1; else hi = mid; }
    gstart[g] = lo;
}

// 4 waves: each wave sums rows i = s+wave, s+wave+4, ...; lane covers ch = lane*4..+3. LDS reduce.
__global__ __launch_bounds__(256) void pool_k(const unsigned short* __restrict__ h,
                                              const int* __restrict__ gstart,
                                              unsigned short* __restrict__ hg) {
    __shared__ float red[4][256];
    int g = blockIdx.x;
    int wave = threadIdx.x >> 6, lane = threadIdx.x & 63;
    int s = gstart[g], e = gstart[g + 1];
    const ushort4* hp = (const ushort4*)h;
    float4 acc = make_float4(0.f, 0.f, 0.f, 0.f);
    for (int i = s + wave; i < e; i += 4) {
        ushort4 v = hp[(size_t)i * 64 + lane];
        acc.x += bf2f(v.x); acc.y += bf2f(v.y); acc.z += bf2f(v.z); acc.w += bf2f(v.w);
    }
    *(float4*)&red[wave][lane * 4] = acc;
    __syncthreads();
    if (wave == 0) {
        float inv = 1.f / fmaxf((float)(e - s), 1.f);
        ushort4 o;
        float v0 = red[0][lane*4+0] + red[1][lane*4+0] + red[2][lane*4+0] + red[3][lane*4+0];
        float v1 = red[0][lane*4+1] + red[1][lane*4+1] + red[2][lane*4+1] + red[3][lane*4+1];
        float v2 = red[0][lane*4+2] + red[1][lane*4+2] + red[2][lane*4+2] + red[3][lane*4+2];
        float v3 = red[0][lane*4+3] + red[1][lane*4+3] + red[2][lane*4+3] + red[3][lane*4+3];
        o.x = f2bf(v0 * inv); o.y = f2bf(v1 * inv); o.z = f2bf(v2 * inv); o.w = f2bf(v3 * inv);
        ((ushort4*)(hg + (size_t)g * NHID))[lane] = o;
    }
}

extern "C" void kernel_launch(void* const* d_in, const int* in_sizes, int n_in,
                              void* d_out, int out_size, void* d_ws, size_t ws_size,
                              hipStream_t stream) {
    const float* x    = (const float*)d_in[0];
    const int*   ei   = (const int*)d_in[1];
    const int*   batch= (const int*)d_in[2];
    const float* W1   = (const float*)d_in[3];
    const float* b1   = (const float*)d_in[4];
    const float* W2   = (const float*)d_in[5];
    const float* b2   = (const float*)d_in[6];
    const float* W3   = (const float*)d_in[7];
    const float* b3   = (const float*)d_in[8];
    const float* Wf1  = (const float*)d_in[9];
    const float* bf1  = (const float*)d_in[10];
    const float* Wf2  = (const float*)d_in[11];
    const float* bf2  = (const float*)d_in[12];
    float* out = (float*)d_out;

    const int* e_src = ei;
    const int* e_dst = ei + NEDGES;

    char* ws = (char*)d_ws;
    size_t off = 0;
    auto alloc = [&](size_t bytes) -> void* {
        void* p = (void*)(ws + off);
        off += (bytes + 255) & ~(size_t)255;
        return p;
    };
    unsigned short* X16 = (unsigned short*)alloc((size_t)NNODES * NFEAT * 2);
    unsigned short* T16 = (unsigned short*)alloc((size_t)NNODES * NHID * 2);
    unsigned short* H16 = (unsigned short*)alloc((size_t)NNODES * NHID * 2);
    unsigned short* Wt1 = (unsigned short*)alloc((size_t)NHID * NFEAT * 2);
    unsigned short* Wt2 = (unsigned short*)alloc((size_t)NHID * NHID * 2);
    unsigned short* Wt3 = (unsigned short*)alloc((size_t)NHID * NHID * 2);
    unsigned short* Wf1t= (unsigned short*)alloc((size_t)NFEAT * NHID * 2);
    unsigned short* Wf2t= (unsigned short*)alloc((size_t)DOUT * NFEAT * 2);
    unsigned short* HG  = (unsigned short*)alloc((size_t)NGRAPH * NHID * 2);
    unsigned short* HR  = (unsigned short*)alloc((size_t)NGRAPH * NFEAT * 2);
    float* dinv = (float*)alloc((size_t)NNODES * 4);
    int*   cnt  = (int*)alloc((size_t)NNODES * 4);
    int*   fill = (int*)alloc((size_t)NNODES * 4);
    int*   rowp = (int*)alloc((size_t)(NNODES + 1) * 4);
    int*   col  = (int*)alloc((size_t)NEDGES * 4);
    float* nrm  = (float*)alloc((size_t)NEDGES * 4);
    int*   part = (int*)alloc((size_t)64 * 4);
    int*   gst  = (int*)alloc((size_t)(NGRAPH + 1) * 4);
    (void)alloc(65536);   // tail pad: keeps GEMM tile over-reads inside d_ws

    const int nb = (NNODES + 1023) / 1024;   // 49

    // ---- CSR + norm ----
    hipLaunchKernelGGL(init_node_k, dim3((NNODES + 255) / 256), dim3(256), 0, stream, cnt, fill, NNODES);
    hipLaunchKernelGGL(edge_hist_k, dim3((NEDGES + 255) / 256), dim3(256), 0, stream, e_dst, cnt, NEDGES);
    hipLaunchKernelGGL(dinv_k, dim3((NNODES + 255) / 256), dim3(256), 0, stream, cnt, dinv, NNODES);
    hipLaunchKernelGGL(scan_block_k, dim3(nb), dim3(1024), 0, stream, cnt, rowp, part, NNODES);
    hipLaunchKernelGGL(scan_part_k, dim3(1), dim3(64), 0, stream, part, nb);
    hipLaunchKernelGGL(scan_add_k, dim3((NNODES + 1 + 255) / 256), dim3(256), 0, stream, rowp, part, NNODES, nb);
    hipLaunchKernelGGL(scatter_k, dim3((NEDGES + 255) / 256), dim3(256), 0, stream,
                       e_src, e_dst, rowp, fill, dinv, col, nrm, NEDGES);

    // ---- casts ----
    hipLaunchKernelGGL(cast_x_k, dim3((NNODES * NFEAT / 8 + 255) / 256), dim3(256), 0, stream,
                       x, X16, NNODES * NFEAT);
    hipLaunchKernelGGL(cast_all_k, dim3((200704 + 255) / 256), dim3(256), 0, stream,
                       W1, W2, W3, Wf1, Wf2, Wt1, Wt2, Wt3, Wf1t, Wf2t);

    const dim3 gemmBlk(256);
    // ---- layer 1 ----
    hipLaunchKernelGGL(gemm_k, dim3((NNODES + 127) / 128, NHID / 128), gemmBlk, 0, stream,
                       X16, Wt1, (const float*)nullptr, T16, NNODES, NHID, NFEAT, 0);
    hipLaunchKernelGGL(agg_k, dim3((NNODES + 3) / 4), dim3(256), 0, stream,
                       T16, rowp, col, nrm, dinv, b1, H16, NNODES);
    // ---- layer 2 ----
    hipLaunchKernelGGL(gemm_k, dim3((NNODES + 127) / 128, NHID / 128), gemmBlk, 0, stream,
                       H16, Wt2, (const float*)nullptr, T16, NNODES, NHID, NHID, 0);
    hipLaunchKernelGGL(agg_k, dim3((NNODES + 3) / 4), dim3(256), 0, stream,
                       T16, rowp, col, nrm, dinv, b2, H16, NNODES);
    // ---- layer 3 ----
    hipLaunchKernelGGL(gemm_k, dim3((NNODES + 127) / 128, NHID / 128), gemmBlk, 0, stream,
                       H16, Wt3, (const float*)nullptr, T16, NNODES, NHID, NHID, 0);
    hipLaunchKernelGGL(agg_k, dim3((NNODES + 3) / 4), dim3(256), 0, stream,
                       T16, rowp, col, nrm, dinv, b3, H16, NNODES);

    // ---- pool ----
    hipLaunchKernelGGL(bounds_k, dim3((NGRAPH + 1 + 255) / 256), dim3(256), 0, stream, batch, gst, NNODES, NGRAPH);
    hipLaunchKernelGGL(pool_k, dim3(NGRAPH), dim3(256), 0, stream, H16, gst, HG);

    // ---- MLP head ----
    hipLaunchKernelGGL(gemm_k, dim3(NGRAPH / 128, 1), gemmBlk, 0, stream,
                       HG, Wf1t, bf1, HR, NGRAPH, NFEAT, NHID, 3);
    hipLaunchKernelGGL(gemm_k, dim3(NGRAPH / 128, 1), gemmBlk, 0, stream,
                       HR, Wf2t, bf2, out, NGRAPH, DOUT, NFEAT, 6);
}